// Round 7
// baseline (267.672 us; speedup 1.0000x reference)
//
#include <hip/hip_runtime.h>
#include <math.h>

#define S_DIM 128
#define H_DIM 8
#define M_TOT (S_DIM * 256)   // 32768

typedef unsigned short ushort_t;
typedef unsigned int   uint32;
typedef __bf16  v8bf  __attribute__((ext_vector_type(8)));
typedef float   v4f   __attribute__((ext_vector_type(4)));
typedef uint32  u32x4 __attribute__((ext_vector_type(4)));

// f32 -> bf16 round-to-nearest-even
__device__ inline ushort_t f2b(float x) {
    unsigned int u = __float_as_uint(x);
    u += 0x7fffu + ((u >> 16) & 1u);
    return (ushort_t)(u >> 16);
}
__device__ inline float b2f(ushort_t h) {
    return __uint_as_float(((unsigned int)h) << 16);
}

// pack 2 f32 -> 1 dword of 2 bf16 (round-half-up), lo16 = e0, hi16 = e1
__device__ inline uint32 pack2(float e0, float e1) {
    return __builtin_amdgcn_perm(__float_as_uint(e1) + 0x8000u,
                                 __float_as_uint(e0) + 0x8000u, 0x07060302u);
}
// split pair into hi-plane dword + lo-plane dword (hi+lo error ~2^-16 rel)
__device__ inline void split_pair(float e0, float e1, uint32& hp, uint32& lp) {
    hp = pack2(e0, e1);
    const float h0 = __uint_as_float(hp << 16);
    const float h1 = __uint_as_float(hp & 0xffff0000u);
    lp = pack2(e0 - h0, e1 - h1);
}
// 8 f32 (two v4f) -> v8bf hi + v8bf lo
__device__ inline void cvt_split8(v4f a, v4f b, v8bf& h, v8bf& l) {
    uint32 h0, h1, h2, h3, l0, l1, l2, l3;
    split_pair(a[0], a[1], h0, l0); split_pair(a[2], a[3], h1, l1);
    split_pair(b[0], b[1], h2, l2); split_pair(b[2], b[3], h3, l3);
    u32x4 hp = {h0, h1, h2, h3}, lp = {l0, l1, l2, l3};
    h = *(v8bf*)&hp; l = *(v8bf*)&lp;
}

// async global->LDS, 16B per lane, wave-uniform LDS base
#define GLDS16(gp, lp) __builtin_amdgcn_global_load_lds( \
    (const __attribute__((address_space(1))) void*)(gp), \
    (__attribute__((address_space(3))) void*)(lp), 16, 0, 0)

// weight split, order: [wq, wg, wk, wv, wo]
__global__ __launch_bounds__(256) void split_w(
    const float* __restrict__ w0, const float* __restrict__ w1,
    const float* __restrict__ w2, const float* __restrict__ w3,
    const float* __restrict__ w4,
    ushort_t* __restrict__ hi, ushort_t* __restrict__ lo)
{
    const float* src;
    switch (blockIdx.y) {
        case 0: src = w0; break; case 1: src = w1; break;
        case 2: src = w2; break; case 3: src = w3; break;
        default: src = w4; break;
    }
    int i = blockIdx.x * 256 + threadIdx.x;
    float4 v = ((const float4*)src)[i];
    ushort4 h, l;
    h.x = f2b(v.x); l.x = f2b(v.x - b2f(h.x));
    h.y = f2b(v.y); l.y = f2b(v.y - b2f(h.y));
    h.z = f2b(v.z); l.z = f2b(v.z - b2f(h.z));
    h.w = f2b(v.w); l.w = f2b(v.w - b2f(h.w));
    size_t base = (size_t)blockIdx.y * 16384;
    ((ushort4*)hi)[base + i] = h;
    ((ushort4*)lo)[base + i] = l;
}

// LDS layout (r2-verified zero-conflict): 64B row stride + seg'=(g+(r>>1))&3.
// 128B row strides are unfixable by 16B swizzles (r3/r4) — f32 A tile is
// therefore stored as TWO [128 x 16 f32] sub-planes (64B rows).
// r6 structure kept: 2-phase LDS double-buffer, one vmcnt(0)+barrier per step.
// This rev: split_x kernel DELETED — gemm_proj stages f32 X directly and
// splits to bf16 hi/lo in registers (pack2/cvt_split8, ~160 VALU/wave/step),
// removing a full 134MB HBM round-trip dispatch.

// ---------------------------------------------------------------------------
// Fused projection GEMM, gridDim.z = 2 (z=0: q+g from q_x, z=1: k+v^T from kv_x).
// 3-term split-bf16 MFMA, 128x128 tile, BK=32, double-buffered.
// LDS per buf: A f32 16KB + Whi 8KB + Wlo 8KB = 32KB; x2 = 64KB (2 blocks/CU).
// Block remap: linear L -> m=(L>>5)*8+(L&7), n=(L>>3)&3.
// ---------------------------------------------------------------------------
__global__ __launch_bounds__(256) void gemm_proj(
    const float* __restrict__ xq, const float* __restrict__ xkv,
    const ushort_t* __restrict__ Whi4, const ushort_t* __restrict__ Wlo4,
    ushort_t* __restrict__ qh, ushort_t* __restrict__ ql,
    ushort_t* __restrict__ kh, ushort_t* __restrict__ kl,
    float* __restrict__ g_out,
    ushort_t* __restrict__ vh,
    float qscale)
{
    __shared__ float    ldsA[2][4096];      // [buf][c2*2048 + row*16 + seg*4]
    __shared__ ushort_t ldsW[2][2][4096];   // [buf][hi/lo][row*32]

    const int z    = blockIdx.z;
    const int L    = blockIdx.x + 4 * blockIdx.y;   // 0..1023
    const int mti  = ((L >> 5) << 3) + (L & 7);     // m-tile 0..255
    const int nti  = (L >> 3) & 3;                  // n-tile 0..3
    const int t    = threadIdx.x;
    const int l    = t & 63;
    const int wv   = t >> 6;
    const int wm   = wv & 1;
    const int wn   = wv >> 1;
    const int idx  = l & 15;
    const int quad = l >> 4;
    const int m0   = mti * 128;
    const int n0   = nti * 128;     // 0..384 over the 512-wide pair

    const float* Asrc = (z ? xkv : xq) + (size_t)m0 * 256;
    const ushort_t* Whi = Whi4 + (size_t)z * 131072 + (size_t)n0 * 256;
    const ushort_t* Wlo = Wlo4 + (size_t)z * 131072 + (size_t)n0 * 256;
    const float scale = z ? 1.f : qscale;

    // A staging map: slot = j*256+t -> [c2][row][seg], r2 swizzle (f32 elems)
    size_t stA[4];
    #pragma unroll
    for (int j = 0; j < 4; ++j) {
        const int slot = j * 256 + t;
        const int c2 = slot >> 9, row = (slot >> 2) & 127, seg = slot & 3;
        const int gseg = (seg - (row >> 1)) & 3;
        stA[j] = (size_t)row * 256 + c2 * 16 + gseg * 4;
    }
    // W staging map (ushort elems)
    size_t stW[2]; int sdW[2];
    #pragma unroll
    for (int i = 0; i < 2; ++i) {
        const int sb   = wv * 128 + i * 64;
        const int slot = sb + l;
        const int row  = slot >> 2;
        const int gseg = ((slot & 3) - (row >> 1)) & 3;
        stW[i] = (size_t)row * 256 + gseg * 8;
        sdW[i] = sb * 8;
    }

    v4f acc[4][4];
    #pragma unroll
    for (int i = 0; i < 4; ++i)
        #pragma unroll
        for (int j = 0; j < 4; ++j) acc[i][j] = (v4f){0.f, 0.f, 0.f, 0.f};

    // prologue: stage k0=0 into buf 0
    #pragma unroll
    for (int j = 0; j < 4; ++j)
        GLDS16(Asrc + stA[j], &ldsA[0][(j * 256 + wv * 64) * 4]);
    #pragma unroll
    for (int i = 0; i < 2; ++i) {
        GLDS16(Whi + stW[i], &ldsW[0][0][sdW[i]]);
        GLDS16(Wlo + stW[i], &ldsW[0][1][sdW[i]]);
    }
    __builtin_amdgcn_s_waitcnt(0);
    __syncthreads();

    const int c2 = quad >> 1;
    const int s0 = (quad & 1) * 2;

    int cur = 0;
    for (int k0 = 0; k0 < 256; k0 += 32) {
        // issue async stage of k0+32 into the other buffer (overlaps compute)
        if (k0 < 224) {
            #pragma unroll
            for (int j = 0; j < 4; ++j)
                GLDS16(Asrc + stA[j] + k0 + 32, &ldsA[cur ^ 1][(j * 256 + wv * 64) * 4]);
            #pragma unroll
            for (int i = 0; i < 2; ++i) {
                GLDS16(Whi + stW[i] + k0 + 32, &ldsW[cur ^ 1][0][sdW[i]]);
                GLDS16(Wlo + stW[i] + k0 + 32, &ldsW[cur ^ 1][1][sdW[i]]);
            }
        }

        v8bf ah[4], al[4], bh[4], bl[4];
        #pragma unroll
        for (int mt = 0; mt < 4; ++mt) {
            const int r  = wm * 64 + mt * 16 + idx;
            const int rb = c2 * 2048 + r * 16;
            v4f fa = *(const v4f*)&ldsA[cur][rb + (((s0 + (r >> 1)) & 3) << 2)];
            v4f fb = *(const v4f*)&ldsA[cur][rb + (((s0 + 1 + (r >> 1)) & 3) << 2)];
            cvt_split8(fa, fb, ah[mt], al[mt]);
        }
        #pragma unroll
        for (int nt = 0; nt < 4; ++nt) {
            const int r   = wn * 64 + nt * 16 + idx;
            const int off = r * 32 + (((quad + (r >> 1)) & 3) << 3);
            bh[nt] = *(const v8bf*)&ldsW[cur][0][off];
            bl[nt] = *(const v8bf*)&ldsW[cur][1][off];
        }

        #pragma unroll
        for (int mt = 0; mt < 4; ++mt)
            #pragma unroll
            for (int nt = 0; nt < 4; ++nt) {
                acc[mt][nt] = __builtin_amdgcn_mfma_f32_16x16x32_bf16(ah[mt], bh[nt], acc[mt][nt], 0, 0, 0);
                acc[mt][nt] = __builtin_amdgcn_mfma_f32_16x16x32_bf16(al[mt], bh[nt], acc[mt][nt], 0, 0, 0);
                acc[mt][nt] = __builtin_amdgcn_mfma_f32_16x16x32_bf16(ah[mt], bl[nt], acc[mt][nt], 0, 0, 0);
            }

        // one drain per step: next-buffer loads landed + all reads of cur done
        __builtin_amdgcn_s_waitcnt(0);
        __syncthreads();
        cur ^= 1;
    }

    ushort_t* dsth = z ? kh : qh;
    ushort_t* dstl = z ? kl : ql;

    #pragma unroll
    for (int mt = 0; mt < 4; ++mt) {
        const int mbase = m0 + wm * 64 + mt * 16 + quad * 4;   // 4 consecutive rows
        const int s = mbase >> 8, r8 = mbase & 255;
        #pragma unroll
        for (int nt = 0; nt < 4; ++nt) {
            const int gcol = n0 + wn * 64 + nt * 16 + idx;     // block-uniform branch
            if (gcol < 256) {
                const int hh = gcol >> 5, c = gcol & 31;
                const size_t di = (((size_t)(s * 8 + hh) * 256) + r8) * 32 + c;
                #pragma unroll
                for (int r = 0; r < 4; ++r) {
                    const float val = acc[mt][nt][r] * scale;
                    const ushort_t hv = f2b(val);
                    dsth[di + (size_t)r * 32] = hv;
                    dstl[di + (size_t)r * 32] = f2b(val - b2f(hv));
                }
            } else if (z == 0) {
                const int gc = gcol - 256;
                #pragma unroll
                for (int r = 0; r < 4; ++r)
                    g_out[(size_t)(mbase + r) * 256 + gc] = acc[mt][nt][r];
            } else {
                const int gc = gcol - 256, hh = gc >> 5, c = gc & 31;
                ushort4 hv4;
                #pragma unroll
                for (int r = 0; r < 4; ++r)
                    ((ushort_t*)&hv4)[r] = f2b(acc[mt][nt][r]);
                const size_t di = (((size_t)(s * 8 + hh) * 32) + c) * 256 + r8;
                *(ushort4*)&vh[di] = hv4;
            }
        }
    }
}

// ---------------------------------------------------------------------------
// Final GEMM: C[M,256] = A_bf16[M,256] @ (Whi+Wlo)[256,256]^T, f32 out.
// 2-term (A single plane), 3 planes, BK=32, double-buffered (2x24KB=48KB).
// ---------------------------------------------------------------------------
__global__ __launch_bounds__(256) void gemm_out(
    const ushort_t* __restrict__ Ah, const ushort_t* __restrict__ Whi,
    const ushort_t* __restrict__ Wlo, float* __restrict__ Cf)
{
    __shared__ ushort_t lds[2][3][128 * 32];   // 48 KB

    const int L    = blockIdx.x + 2 * blockIdx.y;   // 0..511
    const int mti  = ((L >> 4) << 3) + (L & 7);     // 0..255
    const int nti  = (L >> 3) & 1;                  // 0..1
    const int t    = threadIdx.x;
    const int l    = t & 63;
    const int wv   = t >> 6;
    const int wm   = wv & 1;
    const int wn   = wv >> 1;
    const int idx  = l & 15;
    const int quad = l >> 4;
    const int m0   = mti * 128;
    const int n0   = nti * 128;

    const ushort_t* srcs[3] = { Ah + (size_t)m0 * 256,
                                Whi + (size_t)n0 * 256, Wlo + (size_t)n0 * 256 };

    size_t stoff[2]; int sdst[2];
    #pragma unroll
    for (int i = 0; i < 2; ++i) {
        const int sb   = wv * 128 + i * 64;
        const int slot = sb + l;
        const int row  = slot >> 2;
        const int gseg = ((slot & 3) - (row >> 1)) & 3;
        stoff[i] = (size_t)row * 256 + gseg * 8;
        sdst[i]  = sb * 8;
    }

    v4f acc[4][4];
    #pragma unroll
    for (int i = 0; i < 4; ++i)
        #pragma unroll
        for (int j = 0; j < 4; ++j) acc[i][j] = (v4f){0.f, 0.f, 0.f, 0.f};

    // prologue
    #pragma unroll
    for (int b = 0; b < 3; ++b)
        #pragma unroll
        for (int i = 0; i < 2; ++i)
            GLDS16(srcs[b] + stoff[i], &lds[0][b][sdst[i]]);
    __builtin_amdgcn_s_waitcnt(0);
    __syncthreads();

    int cur = 0;
    for (int k0 = 0; k0 < 256; k0 += 32) {
        if (k0 < 224) {
            #pragma unroll
            for (int b = 0; b < 3; ++b)
                #pragma unroll
                for (int i = 0; i < 2; ++i)
                    GLDS16(srcs[b] + stoff[i] + k0 + 32, &lds[cur ^ 1][b][sdst[i]]);
        }

        v8bf ah[4], bh[4], bl[4];
        #pragma unroll
        for (int mt = 0; mt < 4; ++mt) {
            const int r   = wm * 64 + mt * 16 + idx;
            const int off = r * 32 + (((quad + (r >> 1)) & 3) << 3);
            ah[mt] = *(const v8bf*)&lds[cur][0][off];
        }
        #pragma unroll
        for (int nt = 0; nt < 4; ++nt) {
            const int r   = wn * 64 + nt * 16 + idx;
            const int off = r * 32 + (((quad + (r >> 1)) & 3) << 3);
            bh[nt] = *(const v8bf*)&lds[cur][1][off];
            bl[nt] = *(const v8bf*)&lds[cur][2][off];
        }

        #pragma unroll
        for (int mt = 0; mt < 4; ++mt)
            #pragma unroll
            for (int nt = 0; nt < 4; ++nt) {
                acc[mt][nt] = __builtin_amdgcn_mfma_f32_16x16x32_bf16(ah[mt], bh[nt], acc[mt][nt], 0, 0, 0);
                acc[mt][nt] = __builtin_amdgcn_mfma_f32_16x16x32_bf16(ah[mt], bl[nt], acc[mt][nt], 0, 0, 0);
            }

        __builtin_amdgcn_s_waitcnt(0);
        __syncthreads();
        cur ^= 1;
    }

    #pragma unroll
    for (int mt = 0; mt < 4; ++mt) {
        #pragma unroll
        for (int nt = 0; nt < 4; ++nt) {
            const int gcol = n0 + wn * 64 + nt * 16 + idx;
            #pragma unroll
            for (int r = 0; r < 4; ++r) {
                const int grow = m0 + wm * 64 + mt * 16 + quad * 4 + r;
                Cf[(size_t)grow * 256 + gcol] = acc[mt][nt][r];
            }
        }
    }
}

// ---------------------------------------------------------------------------
// MFMA flash attention. One block per (s,h); 4 waves; wave w owns q [64w,64w+64).
// q,k: bf16 hi/lo [sh][row][32] (q prescaled 1/sqrt(32)).
// v:   single bf16 plane, transposed [sh][c=32][ak=256].
// S^T = K·Q^T (D col=q, row=ak), __expf (no max-sub; data bounded),
// P->A-frag via wave-private LDS, O = P·V.
// K(hi/lo)+V for tile c4 staged ONCE per block into LDS via global_load_lds,
// double-buffered: stage of c4+1 issued at loop top, drained by vmcnt(0)+
// barrier at loop bottom — prefetch latency hides under a full iteration.
// LDS layouts (all 64B row stride, r2-verified conflict-free):
//   K planes: [row=64][4 segs of 8], seg' = (g + (row>>1)) & 3
//   V plane:  [kt=2][c=32][4 segs of 8], seg' = (g + (c>>1)) & 3
// l-reduction via shfl_xor; setprio(1) around MFMA clusters.
// Epilogue: /l, sigmoid(g), single bf16 out at [s*256+q][h*32+c].
// ---------------------------------------------------------------------------
__global__ __launch_bounds__(256, 2) void attn_mfma(
    const ushort_t* __restrict__ qh, const ushort_t* __restrict__ ql,
    const ushort_t* __restrict__ kh, const ushort_t* __restrict__ kl,
    const ushort_t* __restrict__ vth,
    const float* __restrict__ b1, const float* __restrict__ b2,
    const float* __restrict__ gbuf,
    ushort_t* __restrict__ oh)
{
    __shared__ __align__(16) uint32   pbuf[4][64 * 36];   // 36 KB
    __shared__ __align__(16) ushort_t kst[2][3][2048];    // 24 KB: [buf][kh,kl,v][4KB]
    __shared__ __align__(16) float    invl[4][64];        // 1 KB

    const int sh = blockIdx.x, s = sh >> 3, h = sh & 7;
    const int t = threadIdx.x, l = t & 63, w = t >> 6;
    const int idx = l & 15, quad = l >> 4;

    const size_t shb = (size_t)sh * 8192;   // 256*32
    const ushort_t* qhp = qh + shb;
    const ushort_t* qlp = ql + shb;
    const ushort_t* khp = kh + shb;
    const ushort_t* klp = kl + shb;
    const ushort_t* vhp = vth + shb;
    const float* b1p = b1 + (size_t)s * 256;
    const float* b2p = b2 + (size_t)h * 65536;

    // staging address precompute (per thread; slot = t covers the block)
    const int ksrow = t >> 2;                         // 0..63
    const int ksseg = ((t & 3) - (ksrow >> 1)) & 3;
    const size_t koff = (size_t)ksrow * 32 + ksseg * 8;
    // V sub-plane map: dest elem t*8 -> [kt = t>>7][c = (t>>2)&31][seg4 = t&3]
    const int vc   = (t >> 2) & 31;
    const int vkt  = t >> 7;
    const int vseg = ((t & 3) - (vc >> 1)) & 3;
    const size_t voff = (size_t)vc * 256 + vkt * 32 + vseg * 8;
    const int wbase = w * 512;                        // wave-uniform LDS elem base

    // Q fragments (hoisted): B-frag, n=q, k=c
    v8bf qfh[4], qfl[4];
    #pragma unroll
    for (int nt = 0; nt < 4; ++nt) {
        const int off = (w * 64 + nt * 16 + idx) * 32 + quad * 8;
        qfh[nt] = *(const v8bf*)(qhp + off);
        qfl[nt] = *(const v8bf*)(qlp + off);
    }

    v4f oacc[4][2];
    #pragma unroll
    for (int mt = 0; mt < 4; ++mt) {
        oacc[mt][0] = (v4f){0.f, 0.f, 0.f, 0.f};
        oacc[mt][1] = (v4f){0.f, 0.f, 0.f, 0.f};
    }
    float lrun[4] = {0.f, 0.f, 0.f, 0.f};

    // prologue: stage c4=0 into buf 0
    GLDS16(khp + koff, &kst[0][0][wbase]);
    GLDS16(klp + koff, &kst[0][1][wbase]);
    GLDS16(vhp + voff, &kst[0][2][wbase]);
    __builtin_amdgcn_s_waitcnt(0);
    __syncthreads();

    for (int c4 = 0; c4 < 4; ++c4) {
        const int ak0 = c4 * 64;
        const int cur = c4 & 1;

        // issue async stage of c4+1 (no VGPR cost; drained at loop bottom)
        if (c4 < 3) {
            const size_t nb = (size_t)(ak0 + 64) * 32;
            GLDS16(khp + nb + koff, &kst[cur ^ 1][0][wbase]);
            GLDS16(klp + nb + koff, &kst[cur ^ 1][1][wbase]);
            GLDS16(vhp + (ak0 + 64) + voff, &kst[cur ^ 1][2][wbase]);
        }

        // K fragments from LDS: A-frag, m=ak, k=c
        v8bf kfh[4], kfl[4];
        #pragma unroll
        for (int at = 0; at < 4; ++at) {
            const int row = at * 16 + idx;
            const int off = row * 32 + (((quad + (row >> 1)) & 3) << 3);
            kfh[at] = *(const v8bf*)&kst[cur][0][off];
            kfl[at] = *(const v8bf*)&kst[cur][1][off];
        }

        // S^T = K·Q^T (3-term split); D col=q(idx), row=ak(quad*4+r)
        v4f sacc[4][4];
        #pragma unroll
        for (int at = 0; at < 4; ++at)
            #pragma unroll
            for (int nt = 0; nt < 4; ++nt)
                sacc[at][nt] = (v4f){0.f, 0.f, 0.f, 0.f};
        __builtin_amdgcn_s_setprio(1);
        #pragma unroll
        for (int at = 0; at < 4; ++at)
            #pragma unroll
            for (int nt = 0; nt < 4; ++nt) {
                sacc[at][nt] = __builtin_amdgcn_mfma_f32_16x16x32_bf16(kfh[at], qfh[nt], sacc[at][nt], 0, 0, 0);
                sacc[at][nt] = __builtin_amdgcn_mfma_f32_16x16x32_bf16(kfl[at], qfh[nt], sacc[at][nt], 0, 0, 0);
                sacc[at][nt] = __builtin_amdgcn_mfma_f32_16x16x32_bf16(kfh[at], qfl[nt], sacc[at][nt], 0, 0, 0);
            }
        __builtin_amdgcn_s_setprio(0);

        // V^T fragments from sub-planed LDS (issued before exp; latency hides)
        v8bf vfh[2][2];
        #pragma unroll
        for (int n2 = 0; n2 < 2; ++n2)
            #pragma unroll
            for (int kt = 0; kt < 2; ++kt) {
                const int c  = n2 * 16 + idx;
                const int sp = (quad + (c >> 1)) & 3;
                vfh[n2][kt] = *(const v8bf*)&kst[cur][2][kt * 1024 + c * 32 + sp * 8];
            }

        v4f b1v[4];
        #pragma unroll
        for (int at = 0; at < 4; ++at)
            b1v[at] = *(const v4f*)(b1p + ak0 + at * 16 + quad * 4);

        // w = exp(s + b1 + b2), accumulate l, pack P to LDS [q][ak]
        #pragma unroll
        for (int at = 0; at < 4; ++at)
            #pragma unroll
            for (int nt = 0; nt < 4; ++nt) {
                const int q = w * 64 + nt * 16 + idx;
                v4f b2v = *(const v4f*)(b2p + (size_t)q * 256 + ak0 + at * 16 + quad * 4);
                float e0 = __expf(b1v[at][0] + b2v[0] + sacc[at][nt][0]);
                float e1 = __expf(b1v[at][1] + b2v[1] + sacc[at][nt][1]);
                float e2 = __expf(b1v[at][2] + b2v[2] + sacc[at][nt][2]);
                float e3 = __expf(b1v[at][3] + b2v[3] + sacc[at][nt][3]);
                lrun[nt] += (e0 + e1) + (e2 + e3);
                // round-half-up bf16 pack: dword = {lo16=e_even, hi16=e_odd}
                uint32 p0 = pack2(e0, e1);
                uint32 p1 = pack2(e2, e3);
                const int dw = (nt * 16 + idx) * 36 + at * 8 + quad * 2;
                *(uint2*)&pbuf[w][dw] = make_uint2(p0, p1);
            }

        // O += P·V ; A-frag of P from LDS (m=q, k=ak); D col=c, row=q
        __builtin_amdgcn_s_setprio(1);
        #pragma unroll
        for (int mt = 0; mt < 4; ++mt)
            #pragma unroll
            for (int kt = 0; kt < 2; ++kt) {
                v8bf pf = *(const v8bf*)&pbuf[w][(mt * 16 + idx) * 36 + kt * 16 + quad * 4];
                #pragma unroll
                for (int n2 = 0; n2 < 2; ++n2)
                    oacc[mt][n2] = __builtin_amdgcn_mfma_f32_16x16x32_bf16(pf, vfh[n2][kt], oacc[mt][n2], 0, 0, 0);
            }
        __builtin_amdgcn_s_setprio(0);

        // drain the async stage of c4+1, publish buffer to all waves
        __builtin_amdgcn_s_waitcnt(0);
        __syncthreads();
    }

    // finalize l: cross-quad sum via shfl_xor butterflies (lanes idx, idx+16,
    // idx+32, idx+48 hold the 4 quad-partials of q-row nt*16+idx)
    #pragma unroll
    for (int nt = 0; nt < 4; ++nt) {
        float v = lrun[nt];
        v += __shfl_xor(v, 16, 64);
        v += __shfl_xor(v, 32, 64);
        if (quad == 0) invl[w][nt * 16 + idx] = 1.f / v;
    }

    // epilogue: o = (O/l) * sigmoid(g), single bf16 out at [s*256+q][h*32+c]
    #pragma unroll
    for (int mt = 0; mt < 4; ++mt) {
        v4f iv = *(const v4f*)&invl[w][mt * 16 + quad * 4];
        #pragma unroll
        for (int n2 = 0; n2 < 2; ++n2) {
            const int c = n2 * 16 + idx;
            #pragma unroll
            for (int r = 0; r < 4; ++r) {
                const int q = w * 64 + mt * 16 + quad * 4 + r;
                const size_t gi = (size_t)(s * 256 + q) * 256 + h * 32 + c;
                const float gv = gbuf[gi];
                const float sig = 1.f / (1.f + __expf(-gv));
                oh[gi] = f2b(oacc[mt][n2][r] * iv[r] * sig);
            }
        }
    }
}

// ---------------------------------------------------------------------------
extern "C" void kernel_launch(void* const* d_in, const int* in_sizes, int n_in,
                              void* d_out, int out_size, void* d_ws, size_t ws_size,
                              hipStream_t stream)
{
    const float* q_x   = (const float*)d_in[0];
    const float* kv_x  = (const float*)d_in[1];
    const float* bias1 = (const float*)d_in[2];
    const float* bias2 = (const float*)d_in[3];
    const float* wq    = (const float*)d_in[4];
    const float* wk    = (const float*)d_in[5];
    const float* wv    = (const float*)d_in[6];
    const float* wg    = (const float*)d_in[7];
    const float* wo    = (const float*)d_in[8];
    float* out = (float*)d_out;

    const size_t BUF = (size_t)M_TOT * 256;   // 8388608 elems

    float*    g_buf = (float*)d_ws;                      // 33.5 MB
    ushort_t* p     = (ushort_t*)(g_buf + BUF);
    ushort_t* qhb = p;            ushort_t* qlb = qhb + BUF;
    ushort_t* khb = qlb + BUF;    ushort_t* klb = khb + BUF;
    ushort_t* vhb = klb + BUF;
    ushort_t* ohb = vhb + BUF;
    ushort_t* w_hi = ohb + BUF;
    ushort_t* w_lo = w_hi + 5 * 65536;

    const float qscale = 0.17677669529663689f;   // 1/sqrt(32)

    // weight splits, stacked order [wq, wg, wk, wv, wo]
    split_w<<<dim3(64, 5), 256, 0, stream>>>(wq, wg, wk, wv, wo, w_hi, w_lo);

    // both fused projections in one dispatch (z=0: q+g, z=1: k+v^T);
    // X hi/lo split fused into A-staging (split_x kernel removed)
    gemm_proj<<<dim3(4, 256, 2), 256, 0, stream>>>(
        q_x, kv_x, w_hi, w_lo, qhb, qlb, khb, klb, g_buf, vhb, qscale);

    attn_mfma<<<S_DIM * H_DIM, 256, 0, stream>>>(
        qhb, qlb, khb, klb, vhb, bias1, bias2, g_buf, ohb);

    // o -> out (2-term: o single plane, W split)
    gemm_out<<<dim3(2, 256), 256, 0, stream>>>(
        ohb, w_hi + 4 * 65536, w_lo + 4 * 65536, out);
}

// Round 8
// 265.230 us; speedup vs baseline: 1.0092x; 1.0092x over previous
//
#include <hip/hip_runtime.h>
#include <math.h>

#define S_DIM 128
#define H_DIM 8
#define M_TOT (S_DIM * 256)   // 32768

typedef unsigned short ushort_t;
typedef unsigned int   uint32;
typedef __bf16  v8bf  __attribute__((ext_vector_type(8)));
typedef float   v4f   __attribute__((ext_vector_type(4)));

// f32 -> bf16 round-to-nearest-even
__device__ inline ushort_t f2b(float x) {
    unsigned int u = __float_as_uint(x);
    u += 0x7fffu + ((u >> 16) & 1u);
    return (ushort_t)(u >> 16);
}
__device__ inline float b2f(ushort_t h) {
    return __uint_as_float(((unsigned int)h) << 16);
}

// pack 2 f32 -> 1 dword of 2 bf16 (round-half-up), lo16 = e0, hi16 = e1
__device__ inline uint32 pack2(float e0, float e1) {
    return __builtin_amdgcn_perm(__float_as_uint(e1) + 0x8000u,
                                 __float_as_uint(e0) + 0x8000u, 0x07060302u);
}
// split pair into hi-plane dword + lo-plane dword (hi+lo error ~2^-16 rel)
__device__ inline void split_pair(float e0, float e1, uint32& hp, uint32& lp) {
    hp = pack2(e0, e1);
    const float h0 = __uint_as_float(hp << 16);
    const float h1 = __uint_as_float(hp & 0xffff0000u);
    lp = pack2(e0 - h0, e1 - h1);
}
// float4 -> 2 hi dwords + 2 lo dwords
__device__ inline void split4(v4f a, uint32& h0, uint32& h1, uint32& l0, uint32& l1) {
    split_pair(a[0], a[1], h0, l0);
    split_pair(a[2], a[3], h1, l1);
}

// async global->LDS, 16B per lane, wave-uniform LDS base
#define GLDS16(gp, lp) __builtin_amdgcn_global_load_lds( \
    (const __attribute__((address_space(1))) void*)(gp), \
    (__attribute__((address_space(3))) void*)(lp), 16, 0, 0)

// weight split, order: [wq, wg, wk, wv, wo]
__global__ __launch_bounds__(256) void split_w(
    const float* __restrict__ w0, const float* __restrict__ w1,
    const float* __restrict__ w2, const float* __restrict__ w3,
    const float* __restrict__ w4,
    ushort_t* __restrict__ hi, ushort_t* __restrict__ lo)
{
    const float* src;
    switch (blockIdx.y) {
        case 0: src = w0; break; case 1: src = w1; break;
        case 2: src = w2; break; case 3: src = w3; break;
        default: src = w4; break;
    }
    int i = blockIdx.x * 256 + threadIdx.x;
    float4 v = ((const float4*)src)[i];
    ushort4 h, l;
    h.x = f2b(v.x); l.x = f2b(v.x - b2f(h.x));
    h.y = f2b(v.y); l.y = f2b(v.y - b2f(h.y));
    h.z = f2b(v.z); l.z = f2b(v.z - b2f(h.z));
    h.w = f2b(v.w); l.w = f2b(v.w - b2f(h.w));
    size_t base = (size_t)blockIdx.y * 16384;
    ((ushort4*)hi)[base + i] = h;
    ((ushort4*)lo)[base + i] = l;
}

// LDS layout (r2-verified zero-conflict): bf16 planes, 64B row stride,
// global seg g of row r at LDS seg (g + (r>>1)) & 3.
// r7 lesson: f32-in-LDS + per-fragment split = conflicts (2.1M) + VALU on the
// ds_read->MFMA path (VALUBusy 38, MfmaUtil 21). This rev (T14): A staged
// global->REG->split->ds_write bf16; loads issued at loop top (latency under
// MFMA), split+write after the MFMA cluster (in the drain window). Fragment
// reads identical to r6 (bf16, 0-conflict), zero VALU before MFMA.

// ---------------------------------------------------------------------------
// Fused projection GEMM, gridDim.z = 2 (z=0: q+g from q_x, z=1: k+v^T from kv_x).
// 3-term split-bf16 MFMA, 128x128 tile, BK=32, 2-phase double-buffer.
// LDS per buf: A hi 8KB + A lo 8KB + W hi 8KB + W lo 8KB = 32KB; x2 = 64KB.
// X hi/lo split fused into staging (split_x kernel deleted).
// Block remap: linear L -> m=(L>>5)*8+(L&7), n=(L>>3)&3.
// ---------------------------------------------------------------------------
__global__ __launch_bounds__(256) void gemm_proj(
    const float* __restrict__ xq, const float* __restrict__ xkv,
    const ushort_t* __restrict__ Whi4, const ushort_t* __restrict__ Wlo4,
    ushort_t* __restrict__ qh, ushort_t* __restrict__ ql,
    ushort_t* __restrict__ kh, ushort_t* __restrict__ kl,
    float* __restrict__ g_out,
    ushort_t* __restrict__ vh,
    float qscale)
{
    __shared__ ushort_t ldsA[2][2][4096];   // [buf][hi/lo][row*32] = 32 KB
    __shared__ ushort_t ldsW[2][2][4096];   // [buf][hi/lo][row*32] = 32 KB

    const int z    = blockIdx.z;
    const int L    = blockIdx.x + 4 * blockIdx.y;   // 0..1023
    const int mti  = ((L >> 5) << 3) + (L & 7);     // m-tile 0..255
    const int nti  = (L >> 3) & 3;                  // n-tile 0..3
    const int t    = threadIdx.x;
    const int l    = t & 63;
    const int wv   = t >> 6;
    const int wm   = wv & 1;
    const int wn   = wv >> 1;
    const int idx  = l & 15;
    const int quad = l >> 4;
    const int m0   = mti * 128;
    const int n0   = nti * 128;     // 0..384 over the 512-wide pair

    const float* Asrc = (z ? xkv : xq) + (size_t)m0 * 256;
    const ushort_t* Whi = Whi4 + (size_t)z * 131072 + (size_t)n0 * 256;
    const ushort_t* Wlo = Wlo4 + (size_t)z * 131072 + (size_t)n0 * 256;
    const float scale = z ? 1.f : qscale;

    // A reg-staging map: slot = j*256+t -> row = slot>>3, c8 = slot&7
    // (float4 c8 of row; per-instruction coalesced in 128B runs).
    // ds_write dest: seg = c8>>1, half = c8&1, seg' = (seg + (row>>1)) & 3.
    size_t agoff[4]; int adoff[4];
    #pragma unroll
    for (int j = 0; j < 4; ++j) {
        const int slot = j * 256 + t;
        const int row = slot >> 3, c8 = slot & 7;
        agoff[j] = (size_t)row * 256 + c8 * 4;
        const int segp = ((c8 >> 1) + (row >> 1)) & 3;
        adoff[j] = row * 32 + segp * 8 + (c8 & 1) * 4;
    }
    // W staging map (ushort elems), r2 swizzle
    size_t stW[2]; int sdW[2];
    #pragma unroll
    for (int i = 0; i < 2; ++i) {
        const int sb   = wv * 128 + i * 64;
        const int slot = sb + l;
        const int row  = slot >> 2;
        const int gseg = ((slot & 3) - (row >> 1)) & 3;
        stW[i] = (size_t)row * 256 + gseg * 8;
        sdW[i] = sb * 8;
    }

    v4f acc[4][4];
    #pragma unroll
    for (int i = 0; i < 4; ++i)
        #pragma unroll
        for (int j = 0; j < 4; ++j) acc[i][j] = (v4f){0.f, 0.f, 0.f, 0.f};

    // prologue: tile 0 — A via reg+split, W via GLDS
    {
        v4f areg[4];
        #pragma unroll
        for (int j = 0; j < 4; ++j)
            areg[j] = *(const v4f*)(Asrc + agoff[j]);
        #pragma unroll
        for (int i = 0; i < 2; ++i) {
            GLDS16(Whi + stW[i], &ldsW[0][0][sdW[i]]);
            GLDS16(Wlo + stW[i], &ldsW[0][1][sdW[i]]);
        }
        #pragma unroll
        for (int j = 0; j < 4; ++j) {
            uint32 h0, h1, l0, l1;
            split4(areg[j], h0, h1, l0, l1);
            *(uint2*)&ldsA[0][0][adoff[j]] = make_uint2(h0, h1);
            *(uint2*)&ldsA[0][1][adoff[j]] = make_uint2(l0, l1);
        }
        __builtin_amdgcn_s_waitcnt(0);
        __syncthreads();
    }

    int cur = 0;
    for (int k0 = 0; k0 < 256; k0 += 32) {
        // issue next-tile loads early: A f32 -> regs, W -> GLDS into buf^1
        v4f anext[4];
        if (k0 < 224) {
            #pragma unroll
            for (int j = 0; j < 4; ++j)
                anext[j] = *(const v4f*)(Asrc + agoff[j] + k0 + 32);
            #pragma unroll
            for (int i = 0; i < 2; ++i) {
                GLDS16(Whi + stW[i] + k0 + 32, &ldsW[cur ^ 1][0][sdW[i]]);
                GLDS16(Wlo + stW[i] + k0 + 32, &ldsW[cur ^ 1][1][sdW[i]]);
            }
        }

        // fragments from buf[cur] — r6 addressing, bf16, 0-conflict
        v8bf ah[4], al[4], bh[4], bl[4];
        #pragma unroll
        for (int mt = 0; mt < 4; ++mt) {
            const int r   = wm * 64 + mt * 16 + idx;
            const int off = r * 32 + (((quad + (r >> 1)) & 3) << 3);
            ah[mt] = *(const v8bf*)&ldsA[cur][0][off];
            al[mt] = *(const v8bf*)&ldsA[cur][1][off];
        }
        #pragma unroll
        for (int nt = 0; nt < 4; ++nt) {
            const int r   = wn * 64 + nt * 16 + idx;
            const int off = r * 32 + (((quad + (r >> 1)) & 3) << 3);
            bh[nt] = *(const v8bf*)&ldsW[cur][0][off];
            bl[nt] = *(const v8bf*)&ldsW[cur][1][off];
        }

        #pragma unroll
        for (int mt = 0; mt < 4; ++mt)
            #pragma unroll
            for (int nt = 0; nt < 4; ++nt) {
                acc[mt][nt] = __builtin_amdgcn_mfma_f32_16x16x32_bf16(ah[mt], bh[nt], acc[mt][nt], 0, 0, 0);
                acc[mt][nt] = __builtin_amdgcn_mfma_f32_16x16x32_bf16(al[mt], bh[nt], acc[mt][nt], 0, 0, 0);
                acc[mt][nt] = __builtin_amdgcn_mfma_f32_16x16x32_bf16(ah[mt], bl[nt], acc[mt][nt], 0, 0, 0);
            }

        // write-late: split next A tile into buf^1 (overlapped with drain)
        if (k0 < 224) {
            #pragma unroll
            for (int j = 0; j < 4; ++j) {
                uint32 h0, h1, l0, l1;
                split4(anext[j], h0, h1, l0, l1);
                *(uint2*)&ldsA[cur ^ 1][0][adoff[j]] = make_uint2(h0, h1);
                *(uint2*)&ldsA[cur ^ 1][1][adoff[j]] = make_uint2(l0, l1);
            }
        }

        // one drain per step: W GLDS landed + ds_writes done + reads of cur done
        __builtin_amdgcn_s_waitcnt(0);
        __syncthreads();
        cur ^= 1;
    }

    ushort_t* dsth = z ? kh : qh;
    ushort_t* dstl = z ? kl : ql;

    #pragma unroll
    for (int mt = 0; mt < 4; ++mt) {
        const int mbase = m0 + wm * 64 + mt * 16 + quad * 4;   // 4 consecutive rows
        const int s = mbase >> 8, r8 = mbase & 255;
        #pragma unroll
        for (int nt = 0; nt < 4; ++nt) {
            const int gcol = n0 + wn * 64 + nt * 16 + idx;     // block-uniform branch
            if (gcol < 256) {
                const int hh = gcol >> 5, c = gcol & 31;
                const size_t di = (((size_t)(s * 8 + hh) * 256) + r8) * 32 + c;
                #pragma unroll
                for (int r = 0; r < 4; ++r) {
                    const float val = acc[mt][nt][r] * scale;
                    const ushort_t hv = f2b(val);
                    dsth[di + (size_t)r * 32] = hv;
                    dstl[di + (size_t)r * 32] = f2b(val - b2f(hv));
                }
            } else if (z == 0) {
                const int gc = gcol - 256;
                #pragma unroll
                for (int r = 0; r < 4; ++r)
                    g_out[(size_t)(mbase + r) * 256 + gc] = acc[mt][nt][r];
            } else {
                const int gc = gcol - 256, hh = gc >> 5, c = gc & 31;
                ushort4 hv4;
                #pragma unroll
                for (int r = 0; r < 4; ++r)
                    ((ushort_t*)&hv4)[r] = f2b(acc[mt][nt][r]);
                const size_t di = (((size_t)(s * 8 + hh) * 32) + c) * 256 + r8;
                *(ushort4*)&vh[di] = hv4;
            }
        }
    }
}

// ---------------------------------------------------------------------------
// Final GEMM: C[M,256] = A_bf16[M,256] @ (Whi+Wlo)[256,256]^T, f32 out.
// 2-term (A single plane), 3 planes, BK=32, double-buffered (2x24KB=48KB).
// ---------------------------------------------------------------------------
__global__ __launch_bounds__(256) void gemm_out(
    const ushort_t* __restrict__ Ah, const ushort_t* __restrict__ Whi,
    const ushort_t* __restrict__ Wlo, float* __restrict__ Cf)
{
    __shared__ ushort_t lds[2][3][128 * 32];   // 48 KB

    const int L    = blockIdx.x + 2 * blockIdx.y;   // 0..511
    const int mti  = ((L >> 4) << 3) + (L & 7);     // 0..255
    const int nti  = (L >> 3) & 1;                  // 0..1
    const int t    = threadIdx.x;
    const int l    = t & 63;
    const int wv   = t >> 6;
    const int wm   = wv & 1;
    const int wn   = wv >> 1;
    const int idx  = l & 15;
    const int quad = l >> 4;
    const int m0   = mti * 128;
    const int n0   = nti * 128;

    const ushort_t* srcs[3] = { Ah + (size_t)m0 * 256,
                                Whi + (size_t)n0 * 256, Wlo + (size_t)n0 * 256 };

    size_t stoff[2]; int sdst[2];
    #pragma unroll
    for (int i = 0; i < 2; ++i) {
        const int sb   = wv * 128 + i * 64;
        const int slot = sb + l;
        const int row  = slot >> 2;
        const int gseg = ((slot & 3) - (row >> 1)) & 3;
        stoff[i] = (size_t)row * 256 + gseg * 8;
        sdst[i]  = sb * 8;
    }

    v4f acc[4][4];
    #pragma unroll
    for (int i = 0; i < 4; ++i)
        #pragma unroll
        for (int j = 0; j < 4; ++j) acc[i][j] = (v4f){0.f, 0.f, 0.f, 0.f};

    // prologue
    #pragma unroll
    for (int b = 0; b < 3; ++b)
        #pragma unroll
        for (int i = 0; i < 2; ++i)
            GLDS16(srcs[b] + stoff[i], &lds[0][b][sdst[i]]);
    __builtin_amdgcn_s_waitcnt(0);
    __syncthreads();

    int cur = 0;
    for (int k0 = 0; k0 < 256; k0 += 32) {
        if (k0 < 224) {
            #pragma unroll
            for (int b = 0; b < 3; ++b)
                #pragma unroll
                for (int i = 0; i < 2; ++i)
                    GLDS16(srcs[b] + stoff[i] + k0 + 32, &lds[cur ^ 1][b][sdst[i]]);
        }

        v8bf ah[4], bh[4], bl[4];
        #pragma unroll
        for (int mt = 0; mt < 4; ++mt) {
            const int r   = wm * 64 + mt * 16 + idx;
            const int off = r * 32 + (((quad + (r >> 1)) & 3) << 3);
            ah[mt] = *(const v8bf*)&lds[cur][0][off];
        }
        #pragma unroll
        for (int nt = 0; nt < 4; ++nt) {
            const int r   = wn * 64 + nt * 16 + idx;
            const int off = r * 32 + (((quad + (r >> 1)) & 3) << 3);
            bh[nt] = *(const v8bf*)&lds[cur][1][off];
            bl[nt] = *(const v8bf*)&lds[cur][2][off];
        }

        #pragma unroll
        for (int mt = 0; mt < 4; ++mt)
            #pragma unroll
            for (int nt = 0; nt < 4; ++nt) {
                acc[mt][nt] = __builtin_amdgcn_mfma_f32_16x16x32_bf16(ah[mt], bh[nt], acc[mt][nt], 0, 0, 0);
                acc[mt][nt] = __builtin_amdgcn_mfma_f32_16x16x32_bf16(ah[mt], bl[nt], acc[mt][nt], 0, 0, 0);
            }

        __builtin_amdgcn_s_waitcnt(0);
        __syncthreads();
        cur ^= 1;
    }

    #pragma unroll
    for (int mt = 0; mt < 4; ++mt) {
        #pragma unroll
        for (int nt = 0; nt < 4; ++nt) {
            const int gcol = n0 + wn * 64 + nt * 16 + idx;
            #pragma unroll
            for (int r = 0; r < 4; ++r) {
                const int grow = m0 + wm * 64 + mt * 16 + quad * 4 + r;
                Cf[(size_t)grow * 256 + gcol] = acc[mt][nt][r];
            }
        }
    }
}

// ---------------------------------------------------------------------------
// MFMA flash attention. One block per (s,h); 4 waves; wave w owns q [64w,64w+64).
// q,k: bf16 hi/lo [sh][row][32] (q prescaled 1/sqrt(32)).
// v:   single bf16 plane, transposed [sh][c=32][ak=256].
// S^T = K·Q^T (D col=q, row=ak), __expf (no max-sub; data bounded),
// P->A-frag via wave-private LDS, O = P·V.
// K(hi/lo)+V for tile c4 staged ONCE per block into LDS via global_load_lds,
// double-buffered: stage of c4+1 issued at loop top, drained by vmcnt(0)+
// barrier at loop bottom — prefetch latency hides under a full iteration.
// LDS layouts (all 64B row stride, r2-verified conflict-free):
//   K planes: [row=64][4 segs of 8], seg' = (g + (row>>1)) & 3
//   V plane:  [kt=2][c=32][4 segs of 8], seg' = (g + (c>>1)) & 3
// l-reduction via shfl_xor; setprio(1) around MFMA clusters.
// Epilogue: /l, sigmoid(g), single bf16 out at [s*256+q][h*32+c].
// ---------------------------------------------------------------------------
__global__ __launch_bounds__(256, 2) void attn_mfma(
    const ushort_t* __restrict__ qh, const ushort_t* __restrict__ ql,
    const ushort_t* __restrict__ kh, const ushort_t* __restrict__ kl,
    const ushort_t* __restrict__ vth,
    const float* __restrict__ b1, const float* __restrict__ b2,
    const float* __restrict__ gbuf,
    ushort_t* __restrict__ oh)
{
    __shared__ __align__(16) uint32   pbuf[4][64 * 36];   // 36 KB
    __shared__ __align__(16) ushort_t kst[2][3][2048];    // 24 KB: [buf][kh,kl,v][4KB]
    __shared__ __align__(16) float    invl[4][64];        // 1 KB

    const int sh = blockIdx.x, s = sh >> 3, h = sh & 7;
    const int t = threadIdx.x, l = t & 63, w = t >> 6;
    const int idx = l & 15, quad = l >> 4;

    const size_t shb = (size_t)sh * 8192;   // 256*32
    const ushort_t* qhp = qh + shb;
    const ushort_t* qlp = ql + shb;
    const ushort_t* khp = kh + shb;
    const ushort_t* klp = kl + shb;
    const ushort_t* vhp = vth + shb;
    const float* b1p = b1 + (size_t)s * 256;
    const float* b2p = b2 + (size_t)h * 65536;

    // staging address precompute (per thread; slot = t covers the block)
    const int ksrow = t >> 2;                         // 0..63
    const int ksseg = ((t & 3) - (ksrow >> 1)) & 3;
    const size_t koff = (size_t)ksrow * 32 + ksseg * 8;
    // V sub-plane map: dest elem t*8 -> [kt = t>>7][c = (t>>2)&31][seg4 = t&3]
    const int vc   = (t >> 2) & 31;
    const int vkt  = t >> 7;
    const int vseg = ((t & 3) - (vc >> 1)) & 3;
    const size_t voff = (size_t)vc * 256 + vkt * 32 + vseg * 8;
    const int wbase = w * 512;                        // wave-uniform LDS elem base

    // Q fragments (hoisted): B-frag, n=q, k=c
    v8bf qfh[4], qfl[4];
    #pragma unroll
    for (int nt = 0; nt < 4; ++nt) {
        const int off = (w * 64 + nt * 16 + idx) * 32 + quad * 8;
        qfh[nt] = *(const v8bf*)(qhp + off);
        qfl[nt] = *(const v8bf*)(qlp + off);
    }

    v4f oacc[4][2];
    #pragma unroll
    for (int mt = 0; mt < 4; ++mt) {
        oacc[mt][0] = (v4f){0.f, 0.f, 0.f, 0.f};
        oacc[mt][1] = (v4f){0.f, 0.f, 0.f, 0.f};
    }
    float lrun[4] = {0.f, 0.f, 0.f, 0.f};

    // prologue: stage c4=0 into buf 0
    GLDS16(khp + koff, &kst[0][0][wbase]);
    GLDS16(klp + koff, &kst[0][1][wbase]);
    GLDS16(vhp + voff, &kst[0][2][wbase]);
    __builtin_amdgcn_s_waitcnt(0);
    __syncthreads();

    for (int c4 = 0; c4 < 4; ++c4) {
        const int ak0 = c4 * 64;
        const int cur = c4 & 1;

        // issue async stage of c4+1 (no VGPR cost; drained at loop bottom)
        if (c4 < 3) {
            const size_t nb = (size_t)(ak0 + 64) * 32;
            GLDS16(khp + nb + koff, &kst[cur ^ 1][0][wbase]);
            GLDS16(klp + nb + koff, &kst[cur ^ 1][1][wbase]);
            GLDS16(vhp + (ak0 + 64) + voff, &kst[cur ^ 1][2][wbase]);
        }

        // K fragments from LDS: A-frag, m=ak, k=c
        v8bf kfh[4], kfl[4];
        #pragma unroll
        for (int at = 0; at < 4; ++at) {
            const int row = at * 16 + idx;
            const int off = row * 32 + (((quad + (row >> 1)) & 3) << 3);
            kfh[at] = *(const v8bf*)&kst[cur][0][off];
            kfl[at] = *(const v8bf*)&kst[cur][1][off];
        }

        // S^T = K·Q^T (3-term split); D col=q(idx), row=ak(quad*4+r)
        v4f sacc[4][4];
        #pragma unroll
        for (int at = 0; at < 4; ++at)
            #pragma unroll
            for (int nt = 0; nt < 4; ++nt)
                sacc[at][nt] = (v4f){0.f, 0.f, 0.f, 0.f};
        __builtin_amdgcn_s_setprio(1);
        #pragma unroll
        for (int at = 0; at < 4; ++at)
            #pragma unroll
            for (int nt = 0; nt < 4; ++nt) {
                sacc[at][nt] = __builtin_amdgcn_mfma_f32_16x16x32_bf16(kfh[at], qfh[nt], sacc[at][nt], 0, 0, 0);
                sacc[at][nt] = __builtin_amdgcn_mfma_f32_16x16x32_bf16(kfl[at], qfh[nt], sacc[at][nt], 0, 0, 0);
                sacc[at][nt] = __builtin_amdgcn_mfma_f32_16x16x32_bf16(kfh[at], qfl[nt], sacc[at][nt], 0, 0, 0);
            }
        __builtin_amdgcn_s_setprio(0);

        // V^T fragments from sub-planed LDS (issued before exp; latency hides)
        v8bf vfh[2][2];
        #pragma unroll
        for (int n2 = 0; n2 < 2; ++n2)
            #pragma unroll
            for (int kt = 0; kt < 2; ++kt) {
                const int c  = n2 * 16 + idx;
                const int sp = (quad + (c >> 1)) & 3;
                vfh[n2][kt] = *(const v8bf*)&kst[cur][2][kt * 1024 + c * 32 + sp * 8];
            }

        v4f b1v[4];
        #pragma unroll
        for (int at = 0; at < 4; ++at)
            b1v[at] = *(const v4f*)(b1p + ak0 + at * 16 + quad * 4);

        // w = exp(s + b1 + b2), accumulate l, pack P to LDS [q][ak]
        #pragma unroll
        for (int at = 0; at < 4; ++at)
            #pragma unroll
            for (int nt = 0; nt < 4; ++nt) {
                const int q = w * 64 + nt * 16 + idx;
                v4f b2v = *(const v4f*)(b2p + (size_t)q * 256 + ak0 + at * 16 + quad * 4);
                float e0 = __expf(b1v[at][0] + b2v[0] + sacc[at][nt][0]);
                float e1 = __expf(b1v[at][1] + b2v[1] + sacc[at][nt][1]);
                float e2 = __expf(b1v[at][2] + b2v[2] + sacc[at][nt][2]);
                float e3 = __expf(b1v[at][3] + b2v[3] + sacc[at][nt][3]);
                lrun[nt] += (e0 + e1) + (e2 + e3);
                // round-half-up bf16 pack: dword = {lo16=e_even, hi16=e_odd}
                uint32 p0 = pack2(e0, e1);
                uint32 p1 = pack2(e2, e3);
                const int dw = (nt * 16 + idx) * 36 + at * 8 + quad * 2;
                *(uint2*)&pbuf[w][dw] = make_uint2(p0, p1);
            }

        // O += P·V ; A-frag of P from LDS (m=q, k=ak); D col=c, row=q
        __builtin_amdgcn_s_setprio(1);
        #pragma unroll
        for (int mt = 0; mt < 4; ++mt)
            #pragma unroll
            for (int kt = 0; kt < 2; ++kt) {
                v8bf pf = *(const v8bf*)&pbuf[w][(mt * 16 + idx) * 36 + kt * 16 + quad * 4];
                #pragma unroll
                for (int n2 = 0; n2 < 2; ++n2)
                    oacc[mt][n2] = __builtin_amdgcn_mfma_f32_16x16x32_bf16(pf, vfh[n2][kt], oacc[mt][n2], 0, 0, 0);
            }
        __builtin_amdgcn_s_setprio(0);

        // drain the async stage of c4+1, publish buffer to all waves
        __builtin_amdgcn_s_waitcnt(0);
        __syncthreads();
    }

    // finalize l: cross-quad sum via shfl_xor butterflies (lanes idx, idx+16,
    // idx+32, idx+48 hold the 4 quad-partials of q-row nt*16+idx)
    #pragma unroll
    for (int nt = 0; nt < 4; ++nt) {
        float v = lrun[nt];
        v += __shfl_xor(v, 16, 64);
        v += __shfl_xor(v, 32, 64);
        if (quad == 0) invl[w][nt * 16 + idx] = 1.f / v;
    }

    // epilogue: o = (O/l) * sigmoid(g), single bf16 out at [s*256+q][h*32+c]
    #pragma unroll
    for (int mt = 0; mt < 4; ++mt) {
        v4f iv = *(const v4f*)&invl[w][mt * 16 + quad * 4];
        #pragma unroll
        for (int n2 = 0; n2 < 2; ++n2) {
            const int c = n2 * 16 + idx;
            #pragma unroll
            for (int r = 0; r < 4; ++r) {
                const int q = w * 64 + mt * 16 + quad * 4 + r;
                const size_t gi = (size_t)(s * 256 + q) * 256 + h * 32 + c;
                const float gv = gbuf[gi];
                const float sig = 1.f / (1.f + __expf(-gv));
                oh[gi] = f2b(oacc[mt][n2][r] * iv[r] * sig);
            }
        }
    }
}

// ---------------------------------------------------------------------------
extern "C" void kernel_launch(void* const* d_in, const int* in_sizes, int n_in,
                              void* d_out, int out_size, void* d_ws, size_t ws_size,
                              hipStream_t stream)
{
    const float* q_x   = (const float*)d_in[0];
    const float* kv_x  = (const float*)d_in[1];
    const float* bias1 = (const float*)d_in[2];
    const float* bias2 = (const float*)d_in[3];
    const float* wq    = (const float*)d_in[4];
    const float* wk    = (const float*)d_in[5];
    const float* wv    = (const float*)d_in[6];
    const float* wg    = (const float*)d_in[7];
    const float* wo    = (const float*)d_in[8];
    float* out = (float*)d_out;

    const size_t BUF = (size_t)M_TOT * 256;   // 8388608 elems

    float*    g_buf = (float*)d_ws;                      // 33.5 MB
    ushort_t* p     = (ushort_t*)(g_buf + BUF);
    ushort_t* qhb = p;            ushort_t* qlb = qhb + BUF;
    ushort_t* khb = qlb + BUF;    ushort_t* klb = khb + BUF;
    ushort_t* vhb = klb + BUF;
    ushort_t* ohb = vhb + BUF;
    ushort_t* w_hi = ohb + BUF;
    ushort_t* w_lo = w_hi + 5 * 65536;

    const float qscale = 0.17677669529663689f;   // 1/sqrt(32)

    // weight splits, stacked order [wq, wg, wk, wv, wo]
    split_w<<<dim3(64, 5), 256, 0, stream>>>(wq, wg, wk, wv, wo, w_hi, w_lo);

    // both fused projections in one dispatch (z=0: q+g, z=1: k+v^T);
    // X hi/lo split fused into A-staging via reg-split (T14)
    gemm_proj<<<dim3(4, 256, 2), 256, 0, stream>>>(
        q_x, kv_x, w_hi, w_lo, qhb, qlb, khb, klb, g_buf, vhb, qscale);

    attn_mfma<<<S_DIM * H_DIM, 256, 0, stream>>>(
        qhb, qlb, khb, klb, vhb, bias1, bias2, g_buf, ohb);

    // o -> out (2-term: o single plane, W split)
    gemm_out<<<dim3(2, 256), 256, 0, stream>>>(
        ohb, w_hi + 4 * 65536, w_lo + 4 * 65536, out);
}

// Round 9
// 261.994 us; speedup vs baseline: 1.0217x; 1.0123x over previous
//
#include <hip/hip_runtime.h>
#include <math.h>

#define S_DIM 128
#define H_DIM 8
#define M_TOT (S_DIM * 256)   // 32768

typedef unsigned short ushort_t;
typedef unsigned int   uint32;
typedef __bf16  v8bf  __attribute__((ext_vector_type(8)));
typedef float   v4f   __attribute__((ext_vector_type(4)));

// f32 -> bf16 round-to-nearest-even
__device__ inline ushort_t f2b(float x) {
    unsigned int u = __float_as_uint(x);
    u += 0x7fffu + ((u >> 16) & 1u);
    return (ushort_t)(u >> 16);
}
__device__ inline float b2f(ushort_t h) {
    return __uint_as_float(((unsigned int)h) << 16);
}

// pack 2 f32 -> 1 dword of 2 bf16 (round-half-up), lo16 = e0, hi16 = e1
__device__ inline uint32 pack2(float e0, float e1) {
    return __builtin_amdgcn_perm(__float_as_uint(e1) + 0x8000u,
                                 __float_as_uint(e0) + 0x8000u, 0x07060302u);
}

// async global->LDS, 16B per lane, wave-uniform LDS base
#define GLDS16(gp, lp) __builtin_amdgcn_global_load_lds( \
    (const __attribute__((address_space(1))) void*)(gp), \
    (__attribute__((address_space(3))) void*)(lp), 16, 0, 0)

// ---------------------------------------------------------------------------
// Merged preprocessing: y<2 -> input split (y=0: q_x, y=1: kv_x);
// y in 2..6 -> weight split [wq, wg, wk, wv, wo] (only blockIdx.x<64 active).
// r7/r8 lesson: this BW-bound split belongs in its own high-occupancy
// streaming dispatch — fusing it into gemm_proj's per-step path cost exactly
// what the dispatch costs (~25us), twice.
// ---------------------------------------------------------------------------
__global__ __launch_bounds__(256) void split_all(
    const float* __restrict__ xq, const float* __restrict__ xkv,
    const float* __restrict__ w0, const float* __restrict__ w1,
    const float* __restrict__ w2, const float* __restrict__ w3,
    const float* __restrict__ w4,
    ushort_t* __restrict__ xhi, ushort_t* __restrict__ xlo,
    ushort_t* __restrict__ whi, ushort_t* __restrict__ wlo)
{
    const int y = blockIdx.y;
    const float* src;
    ushort_t *dh, *dl;
    size_t base;
    int i = blockIdx.x * 256 + threadIdx.x;

    if (y < 2) {
        const size_t BUF4 = (size_t)M_TOT * 64;   // elems/4
        src = y ? xkv : xq;
        base = (size_t)y * BUF4;
        dh = xhi; dl = xlo;
    } else {
        if (blockIdx.x >= 64) return;
        switch (y) {
            case 2: src = w0; break; case 3: src = w1; break;
            case 4: src = w2; break; case 5: src = w3; break;
            default: src = w4; break;
        }
        base = (size_t)(y - 2) * 16384;
        dh = whi; dl = wlo;
    }

    float4 v = ((const float4*)src)[i];
    ushort4 h, l;
    h.x = f2b(v.x); l.x = f2b(v.x - b2f(h.x));
    h.y = f2b(v.y); l.y = f2b(v.y - b2f(h.y));
    h.z = f2b(v.z); l.z = f2b(v.z - b2f(h.z));
    h.w = f2b(v.w); l.w = f2b(v.w - b2f(h.w));
    ((ushort4*)dh)[base + i] = h;
    ((ushort4*)dl)[base + i] = l;
}

// LDS layout (r2-verified zero-conflict): bf16 planes, 64B row stride,
// global seg g of row r at LDS seg (g + (r>>1)) & 3. 128B row strides are
// unfixable by 16B swizzles (r3/r4, permutation-invariant 4.19M cycles).
// Structure: 2-phase LDS double-buffer (r6, best measured: 70.7us) — stage
// k+1 issued BEFORE compute of k, ONE vmcnt(0)+barrier per step.

// ---------------------------------------------------------------------------
// Fused projection GEMM, gridDim.z = 2 (z=0: q+g from xq, z=1: k+v^T from xkv).
// 3-term split-bf16 MFMA, 128x128 tile, BK=32, double-buffered (2x32KB=64KB).
// Pure-g blocks (z=0, nti>=2): 2-term MFMA + 3-plane staging — g feeds
// sigmoid (deriv <= 1/4); dropped ah*bl correction ~5e-4, far under the
// 2^-8 o-plane quantization floor. Pure-v blocks keep 3-term (no margin).
// Block remap: linear L -> m=(L>>5)*8+(L&7), n=(L>>3)&3 — same-A blocks share
// an XCD, 8 apart in dispatch (L2 A-tile reuse).
// ---------------------------------------------------------------------------
__global__ __launch_bounds__(256) void gemm_proj(
    const ushort_t* __restrict__ Xhi, const ushort_t* __restrict__ Xlo,
    const ushort_t* __restrict__ Whi4, const ushort_t* __restrict__ Wlo4,
    ushort_t* __restrict__ qh, ushort_t* __restrict__ ql,
    ushort_t* __restrict__ kh, ushort_t* __restrict__ kl,
    float* __restrict__ g_out,
    ushort_t* __restrict__ vh,
    float qscale)
{
    __shared__ ushort_t lds[2][4][128 * 32];   // [buf][plane][row*32] = 64 KB

    const int z    = blockIdx.z;
    const int L    = blockIdx.x + 4 * blockIdx.y;   // 0..1023
    const int mti  = ((L >> 5) << 3) + (L & 7);     // m-tile 0..255
    const int nti  = (L >> 3) & 3;                  // n-tile 0..3
    const int t    = threadIdx.x;
    const int l    = t & 63;
    const int wv   = t >> 6;
    const int wm   = wv & 1;
    const int wn   = wv >> 1;
    const int idx  = l & 15;
    const int quad = l >> 4;
    const int m0   = mti * 128;
    const int n0   = nti * 128;     // 0..384 over the 512-wide pair

    const bool two_term = (z == 0) && (nti >= 2);   // pure-g blocks

    const size_t BUF = (size_t)M_TOT * 256;
    const ushort_t* Ahi = Xhi + (size_t)z * BUF;
    const ushort_t* Alo = Xlo + (size_t)z * BUF;
    const ushort_t* Whi = Whi4 + (size_t)z * 131072;
    const ushort_t* Wlo = Wlo4 + (size_t)z * 131072;
    const float scale = z ? 1.f : qscale;

    const ushort_t* srcs[4] = { Ahi + (size_t)m0 * 256, Alo + (size_t)m0 * 256,
                                Whi + (size_t)n0 * 256, Wlo + (size_t)n0 * 256 };

    // staging map (per thread, both halves i=0,1): slot -> row/seg, r2 swizzle
    size_t stoff[2]; int sdst[2];
    #pragma unroll
    for (int i = 0; i < 2; ++i) {
        const int sb   = wv * 128 + i * 64;
        const int slot = sb + l;
        const int row  = slot >> 2;
        const int gseg = ((slot & 3) - (row >> 1)) & 3;
        stoff[i] = (size_t)row * 256 + gseg * 8;
        sdst[i]  = sb * 8;
    }

    v4f acc[4][4];
    #pragma unroll
    for (int i = 0; i < 4; ++i)
        #pragma unroll
        for (int j = 0; j < 4; ++j) acc[i][j] = (v4f){0.f, 0.f, 0.f, 0.f};

    // prologue: stage k0=0 into buf 0
    #pragma unroll
    for (int b = 0; b < 4; ++b) {
        if (two_term && b == 3) continue;   // block-uniform
        #pragma unroll
        for (int i = 0; i < 2; ++i)
            GLDS16(srcs[b] + stoff[i], &lds[0][b][sdst[i]]);
    }
    __builtin_amdgcn_s_waitcnt(0);
    __syncthreads();

    int cur = 0;
    for (int k0 = 0; k0 < 256; k0 += 32) {
        // issue async stage of k0+32 into the other buffer (overlaps compute)
        if (k0 < 224) {
            #pragma unroll
            for (int b = 0; b < 4; ++b) {
                if (two_term && b == 3) continue;
                #pragma unroll
                for (int i = 0; i < 2; ++i)
                    GLDS16(srcs[b] + stoff[i] + k0 + 32, &lds[cur ^ 1][b][sdst[i]]);
            }
        }

        v8bf ah[4], al[4], bh[4], bl[4];
        #pragma unroll
        for (int mt = 0; mt < 4; ++mt) {
            const int r   = wm * 64 + mt * 16 + idx;
            const int off = r * 32 + (((quad + (r >> 1)) & 3) << 3);
            ah[mt] = *(const v8bf*)&lds[cur][0][off];
            al[mt] = *(const v8bf*)&lds[cur][1][off];
        }
        #pragma unroll
        for (int nt = 0; nt < 4; ++nt) {
            const int r   = wn * 64 + nt * 16 + idx;
            const int off = r * 32 + (((quad + (r >> 1)) & 3) << 3);
            bh[nt] = *(const v8bf*)&lds[cur][2][off];
            if (!two_term) bl[nt] = *(const v8bf*)&lds[cur][3][off];
        }

        #pragma unroll
        for (int mt = 0; mt < 4; ++mt)
            #pragma unroll
            for (int nt = 0; nt < 4; ++nt) {
                acc[mt][nt] = __builtin_amdgcn_mfma_f32_16x16x32_bf16(ah[mt], bh[nt], acc[mt][nt], 0, 0, 0);
                acc[mt][nt] = __builtin_amdgcn_mfma_f32_16x16x32_bf16(al[mt], bh[nt], acc[mt][nt], 0, 0, 0);
                if (!two_term)
                    acc[mt][nt] = __builtin_amdgcn_mfma_f32_16x16x32_bf16(ah[mt], bl[nt], acc[mt][nt], 0, 0, 0);
            }

        // one drain per step: next-buffer loads landed + all reads of cur done
        __builtin_amdgcn_s_waitcnt(0);
        __syncthreads();
        cur ^= 1;
    }

    ushort_t* dsth = z ? kh : qh;
    ushort_t* dstl = z ? kl : ql;

    #pragma unroll
    for (int mt = 0; mt < 4; ++mt) {
        const int mbase = m0 + wm * 64 + mt * 16 + quad * 4;   // 4 consecutive rows
        const int s = mbase >> 8, r8 = mbase & 255;
        #pragma unroll
        for (int nt = 0; nt < 4; ++nt) {
            const int gcol = n0 + wn * 64 + nt * 16 + idx;     // block-uniform branch
            if (gcol < 256) {
                const int hh = gcol >> 5, c = gcol & 31;
                const size_t di = (((size_t)(s * 8 + hh) * 256) + r8) * 32 + c;
                #pragma unroll
                for (int r = 0; r < 4; ++r) {
                    const float val = acc[mt][nt][r] * scale;
                    const ushort_t hv = f2b(val);
                    dsth[di + (size_t)r * 32] = hv;
                    dstl[di + (size_t)r * 32] = f2b(val - b2f(hv));
                }
            } else if (z == 0) {
                const int gc = gcol - 256;
                #pragma unroll
                for (int r = 0; r < 4; ++r)
                    g_out[(size_t)(mbase + r) * 256 + gc] = acc[mt][nt][r];
            } else {
                const int gc = gcol - 256, hh = gc >> 5, c = gc & 31;
                ushort4 hv4;
                #pragma unroll
                for (int r = 0; r < 4; ++r)
                    ((ushort_t*)&hv4)[r] = f2b(acc[mt][nt][r]);
                const size_t di = (((size_t)(s * 8 + hh) * 32) + c) * 256 + r8;
                *(ushort4*)&vh[di] = hv4;
            }
        }
    }
}

// ---------------------------------------------------------------------------
// Final GEMM: C[M,256] = A_bf16[M,256] @ (Whi+Wlo)[256,256]^T, f32 out.
// 2-term (A single plane), 3 planes, BK=32, double-buffered (2x24KB=48KB).
// ---------------------------------------------------------------------------
__global__ __launch_bounds__(256) void gemm_out(
    const ushort_t* __restrict__ Ah, const ushort_t* __restrict__ Whi,
    const ushort_t* __restrict__ Wlo, float* __restrict__ Cf)
{
    __shared__ ushort_t lds[2][3][128 * 32];   // 48 KB

    const int L    = blockIdx.x + 2 * blockIdx.y;   // 0..511
    const int mti  = ((L >> 4) << 3) + (L & 7);     // 0..255
    const int nti  = (L >> 3) & 1;                  // 0..1
    const int t    = threadIdx.x;
    const int l    = t & 63;
    const int wv   = t >> 6;
    const int wm   = wv & 1;
    const int wn   = wv >> 1;
    const int idx  = l & 15;
    const int quad = l >> 4;
    const int m0   = mti * 128;
    const int n0   = nti * 128;

    const ushort_t* srcs[3] = { Ah + (size_t)m0 * 256,
                                Whi + (size_t)n0 * 256, Wlo + (size_t)n0 * 256 };

    size_t stoff[2]; int sdst[2];
    #pragma unroll
    for (int i = 0; i < 2; ++i) {
        const int sb   = wv * 128 + i * 64;
        const int slot = sb + l;
        const int row  = slot >> 2;
        const int gseg = ((slot & 3) - (row >> 1)) & 3;
        stoff[i] = (size_t)row * 256 + gseg * 8;
        sdst[i]  = sb * 8;
    }

    v4f acc[4][4];
    #pragma unroll
    for (int i = 0; i < 4; ++i)
        #pragma unroll
        for (int j = 0; j < 4; ++j) acc[i][j] = (v4f){0.f, 0.f, 0.f, 0.f};

    // prologue
    #pragma unroll
    for (int b = 0; b < 3; ++b)
        #pragma unroll
        for (int i = 0; i < 2; ++i)
            GLDS16(srcs[b] + stoff[i], &lds[0][b][sdst[i]]);
    __builtin_amdgcn_s_waitcnt(0);
    __syncthreads();

    int cur = 0;
    for (int k0 = 0; k0 < 256; k0 += 32) {
        if (k0 < 224) {
            #pragma unroll
            for (int b = 0; b < 3; ++b)
                #pragma unroll
                for (int i = 0; i < 2; ++i)
                    GLDS16(srcs[b] + stoff[i] + k0 + 32, &lds[cur ^ 1][b][sdst[i]]);
        }

        v8bf ah[4], bh[4], bl[4];
        #pragma unroll
        for (int mt = 0; mt < 4; ++mt) {
            const int r   = wm * 64 + mt * 16 + idx;
            const int off = r * 32 + (((quad + (r >> 1)) & 3) << 3);
            ah[mt] = *(const v8bf*)&lds[cur][0][off];
        }
        #pragma unroll
        for (int nt = 0; nt < 4; ++nt) {
            const int r   = wn * 64 + nt * 16 + idx;
            const int off = r * 32 + (((quad + (r >> 1)) & 3) << 3);
            bh[nt] = *(const v8bf*)&lds[cur][1][off];
            bl[nt] = *(const v8bf*)&lds[cur][2][off];
        }

        #pragma unroll
        for (int mt = 0; mt < 4; ++mt)
            #pragma unroll
            for (int nt = 0; nt < 4; ++nt) {
                acc[mt][nt] = __builtin_amdgcn_mfma_f32_16x16x32_bf16(ah[mt], bh[nt], acc[mt][nt], 0, 0, 0);
                acc[mt][nt] = __builtin_amdgcn_mfma_f32_16x16x32_bf16(ah[mt], bl[nt], acc[mt][nt], 0, 0, 0);
            }

        __builtin_amdgcn_s_waitcnt(0);
        __syncthreads();
        cur ^= 1;
    }

    #pragma unroll
    for (int mt = 0; mt < 4; ++mt) {
        #pragma unroll
        for (int nt = 0; nt < 4; ++nt) {
            const int gcol = n0 + wn * 64 + nt * 16 + idx;
            #pragma unroll
            for (int r = 0; r < 4; ++r) {
                const int grow = m0 + wm * 64 + mt * 16 + quad * 4 + r;
                Cf[(size_t)grow * 256 + gcol] = acc[mt][nt][r];
            }
        }
    }
}

// ---------------------------------------------------------------------------
// MFMA flash attention. One block per (s,h); 4 waves; wave w owns q [64w,64w+64).
// q,k: bf16 hi/lo [sh][row][32] (q prescaled 1/sqrt(32)).
// v:   single bf16 plane, transposed [sh][c=32][ak=256].
// S^T = K·Q^T (D col=q, row=ak), __expf (no max-sub; data bounded),
// P->A-frag via wave-private LDS, O = P·V.
// K(hi/lo)+V for tile c4 staged ONCE per block into LDS via global_load_lds,
// double-buffered: stage of c4+1 issued at loop top, drained by vmcnt(0)+
// barrier at loop bottom — prefetch latency hides under a full iteration.
// LDS layouts (all 64B row stride, r2-verified conflict-free):
//   K planes: [row=64][4 segs of 8], seg' = (g + (row>>1)) & 3
//   V plane:  [kt=2][c=32][4 segs of 8], seg' = (g + (c>>1)) & 3
// l-reduction via shfl_xor; setprio(1) around MFMA clusters.
// Epilogue: /l, sigmoid(g), single bf16 out at [s*256+q][h*32+c].
// ---------------------------------------------------------------------------
__global__ __launch_bounds__(256, 2) void attn_mfma(
    const ushort_t* __restrict__ qh, const ushort_t* __restrict__ ql,
    const ushort_t* __restrict__ kh, const ushort_t* __restrict__ kl,
    const ushort_t* __restrict__ vth,
    const float* __restrict__ b1, const float* __restrict__ b2,
    const float* __restrict__ gbuf,
    ushort_t* __restrict__ oh)
{
    __shared__ __align__(16) uint32   pbuf[4][64 * 36];   // 36 KB
    __shared__ __align__(16) ushort_t kst[2][3][2048];    // 24 KB: [buf][kh,kl,v][4KB]
    __shared__ __align__(16) float    invl[4][64];        // 1 KB

    const int sh = blockIdx.x, s = sh >> 3, h = sh & 7;
    const int t = threadIdx.x, l = t & 63, w = t >> 6;
    const int idx = l & 15, quad = l >> 4;

    const size_t shb = (size_t)sh * 8192;   // 256*32
    const ushort_t* qhp = qh + shb;
    const ushort_t* qlp = ql + shb;
    const ushort_t* khp = kh + shb;
    const ushort_t* klp = kl + shb;
    const ushort_t* vhp = vth + shb;
    const float* b1p = b1 + (size_t)s * 256;
    const float* b2p = b2 + (size_t)h * 65536;

    // staging address precompute (per thread; slot = t covers the block)
    const int ksrow = t >> 2;                         // 0..63
    const int ksseg = ((t & 3) - (ksrow >> 1)) & 3;
    const size_t koff = (size_t)ksrow * 32 + ksseg * 8;
    // V sub-plane map: dest elem t*8 -> [kt = t>>7][c = (t>>2)&31][seg4 = t&3]
    const int vc   = (t >> 2) & 31;
    const int vkt  = t >> 7;
    const int vseg = ((t & 3) - (vc >> 1)) & 3;
    const size_t voff = (size_t)vc * 256 + vkt * 32 + vseg * 8;
    const int wbase = w * 512;                        // wave-uniform LDS elem base

    // Q fragments (hoisted): B-frag, n=q, k=c
    v8bf qfh[4], qfl[4];
    #pragma unroll
    for (int nt = 0; nt < 4; ++nt) {
        const int off = (w * 64 + nt * 16 + idx) * 32 + quad * 8;
        qfh[nt] = *(const v8bf*)(qhp + off);
        qfl[nt] = *(const v8bf*)(qlp + off);
    }

    v4f oacc[4][2];
    #pragma unroll
    for (int mt = 0; mt < 4; ++mt) {
        oacc[mt][0] = (v4f){0.f, 0.f, 0.f, 0.f};
        oacc[mt][1] = (v4f){0.f, 0.f, 0.f, 0.f};
    }
    float lrun[4] = {0.f, 0.f, 0.f, 0.f};

    // prologue: stage c4=0 into buf 0
    GLDS16(khp + koff, &kst[0][0][wbase]);
    GLDS16(klp + koff, &kst[0][1][wbase]);
    GLDS16(vhp + voff, &kst[0][2][wbase]);
    __builtin_amdgcn_s_waitcnt(0);
    __syncthreads();

    for (int c4 = 0; c4 < 4; ++c4) {
        const int ak0 = c4 * 64;
        const int cur = c4 & 1;

        // issue async stage of c4+1 (no VGPR cost; drained at loop bottom)
        if (c4 < 3) {
            const size_t nb = (size_t)(ak0 + 64) * 32;
            GLDS16(khp + nb + koff, &kst[cur ^ 1][0][wbase]);
            GLDS16(klp + nb + koff, &kst[cur ^ 1][1][wbase]);
            GLDS16(vhp + (ak0 + 64) + voff, &kst[cur ^ 1][2][wbase]);
        }

        // K fragments from LDS: A-frag, m=ak, k=c
        v8bf kfh[4], kfl[4];
        #pragma unroll
        for (int at = 0; at < 4; ++at) {
            const int row = at * 16 + idx;
            const int off = row * 32 + (((quad + (row >> 1)) & 3) << 3);
            kfh[at] = *(const v8bf*)&kst[cur][0][off];
            kfl[at] = *(const v8bf*)&kst[cur][1][off];
        }

        // S^T = K·Q^T (3-term split); D col=q(idx), row=ak(quad*4+r)
        v4f sacc[4][4];
        #pragma unroll
        for (int at = 0; at < 4; ++at)
            #pragma unroll
            for (int nt = 0; nt < 4; ++nt)
                sacc[at][nt] = (v4f){0.f, 0.f, 0.f, 0.f};
        __builtin_amdgcn_s_setprio(1);
        #pragma unroll
        for (int at = 0; at < 4; ++at)
            #pragma unroll
            for (int nt = 0; nt < 4; ++nt) {
                sacc[at][nt] = __builtin_amdgcn_mfma_f32_16x16x32_bf16(kfh[at], qfh[nt], sacc[at][nt], 0, 0, 0);
                sacc[at][nt] = __builtin_amdgcn_mfma_f32_16x16x32_bf16(kfl[at], qfh[nt], sacc[at][nt], 0, 0, 0);
                sacc[at][nt] = __builtin_amdgcn_mfma_f32_16x16x32_bf16(kfh[at], qfl[nt], sacc[at][nt], 0, 0, 0);
            }
        __builtin_amdgcn_s_setprio(0);

        // V^T fragments from sub-planed LDS (issued before exp; latency hides)
        v8bf vfh[2][2];
        #pragma unroll
        for (int n2 = 0; n2 < 2; ++n2)
            #pragma unroll
            for (int kt = 0; kt < 2; ++kt) {
                const int c  = n2 * 16 + idx;
                const int sp = (quad + (c >> 1)) & 3;
                vfh[n2][kt] = *(const v8bf*)&kst[cur][2][kt * 1024 + c * 32 + sp * 8];
            }

        v4f b1v[4];
        #pragma unroll
        for (int at = 0; at < 4; ++at)
            b1v[at] = *(const v4f*)(b1p + ak0 + at * 16 + quad * 4);

        // w = exp(s + b1 + b2), accumulate l, pack P to LDS [q][ak]
        #pragma unroll
        for (int at = 0; at < 4; ++at)
            #pragma unroll
            for (int nt = 0; nt < 4; ++nt) {
                const int q = w * 64 + nt * 16 + idx;
                v4f b2v = *(const v4f*)(b2p + (size_t)q * 256 + ak0 + at * 16 + quad * 4);
                float e0 = __expf(b1v[at][0] + b2v[0] + sacc[at][nt][0]);
                float e1 = __expf(b1v[at][1] + b2v[1] + sacc[at][nt][1]);
                float e2 = __expf(b1v[at][2] + b2v[2] + sacc[at][nt][2]);
                float e3 = __expf(b1v[at][3] + b2v[3] + sacc[at][nt][3]);
                lrun[nt] += (e0 + e1) + (e2 + e3);
                // round-half-up bf16 pack: dword = {lo16=e_even, hi16=e_odd}
                uint32 p0 = pack2(e0, e1);
                uint32 p1 = pack2(e2, e3);
                const int dw = (nt * 16 + idx) * 36 + at * 8 + quad * 2;
                *(uint2*)&pbuf[w][dw] = make_uint2(p0, p1);
            }

        // O += P·V ; A-frag of P from LDS (m=q, k=ak); D col=c, row=q
        __builtin_amdgcn_s_setprio(1);
        #pragma unroll
        for (int mt = 0; mt < 4; ++mt)
            #pragma unroll
            for (int kt = 0; kt < 2; ++kt) {
                v8bf pf = *(const v8bf*)&pbuf[w][(mt * 16 + idx) * 36 + kt * 16 + quad * 4];
                #pragma unroll
                for (int n2 = 0; n2 < 2; ++n2)
                    oacc[mt][n2] = __builtin_amdgcn_mfma_f32_16x16x32_bf16(pf, vfh[n2][kt], oacc[mt][n2], 0, 0, 0);
            }
        __builtin_amdgcn_s_setprio(0);

        // drain the async stage of c4+1, publish buffer to all waves
        __builtin_amdgcn_s_waitcnt(0);
        __syncthreads();
    }

    // finalize l: cross-quad sum via shfl_xor butterflies (lanes idx, idx+16,
    // idx+32, idx+48 hold the 4 quad-partials of q-row nt*16+idx)
    #pragma unroll
    for (int nt = 0; nt < 4; ++nt) {
        float v = lrun[nt];
        v += __shfl_xor(v, 16, 64);
        v += __shfl_xor(v, 32, 64);
        if (quad == 0) invl[w][nt * 16 + idx] = 1.f / v;
    }

    // epilogue: o = (O/l) * sigmoid(g), single bf16 out at [s*256+q][h*32+c]
    #pragma unroll
    for (int mt = 0; mt < 4; ++mt) {
        v4f iv = *(const v4f*)&invl[w][mt * 16 + quad * 4];
        #pragma unroll
        for (int n2 = 0; n2 < 2; ++n2) {
            const int c = n2 * 16 + idx;
            #pragma unroll
            for (int r = 0; r < 4; ++r) {
                const int q = w * 64 + mt * 16 + quad * 4 + r;
                const size_t gi = (size_t)(s * 256 + q) * 256 + h * 32 + c;
                const float gv = gbuf[gi];
                const float sig = 1.f / (1.f + __expf(-gv));
                oh[gi] = f2b(oacc[mt][n2][r] * iv[r] * sig);
            }
        }
    }
}

// ---------------------------------------------------------------------------
extern "C" void kernel_launch(void* const* d_in, const int* in_sizes, int n_in,
                              void* d_out, int out_size, void* d_ws, size_t ws_size,
                              hipStream_t stream)
{
    const float* q_x   = (const float*)d_in[0];
    const float* kv_x  = (const float*)d_in[1];
    const float* bias1 = (const float*)d_in[2];
    const float* bias2 = (const float*)d_in[3];
    const float* wq    = (const float*)d_in[4];
    const float* wk    = (const float*)d_in[5];
    const float* wv    = (const float*)d_in[6];
    const float* wg    = (const float*)d_in[7];
    const float* wo    = (const float*)d_in[8];
    float* out = (float*)d_out;

    const size_t BUF = (size_t)M_TOT * 256;   // 8388608 elems

    float*    g_buf = (float*)d_ws;                      // 33.5 MB
    ushort_t* p     = (ushort_t*)(g_buf + BUF);
    ushort_t* qhb = p;            ushort_t* qlb = qhb + BUF;
    ushort_t* khb = qlb + BUF;    ushort_t* klb = khb + BUF;
    ushort_t* vhb = klb + BUF;
    ushort_t* ohb = vhb + BUF;
    ushort_t* xhb = ohb + BUF;    ushort_t* xlb = xhb + 2 * BUF;  // 2 inputs each
    ushort_t* w_hi = xlb + 2 * BUF;
    ushort_t* w_lo = w_hi + 5 * 65536;

    const float qscale = 0.17677669529663689f;   // 1/sqrt(32)

    // merged preprocessing: inputs (y<2) + weights [wq,wg,wk,wv,wo] (y=2..6)
    split_all<<<dim3(8192, 7), 256, 0, stream>>>(
        q_x, kv_x, wq, wg, wk, wv, wo, xhb, xlb, w_hi, w_lo);

    // both fused projections in one dispatch (z=0: q+g, z=1: k+v^T)
    gemm_proj<<<dim3(4, 256, 2), 256, 0, stream>>>(
        xhb, xlb, w_hi, w_lo, qhb, qlb, khb, klb, g_buf, vhb, qscale);

    attn_mfma<<<S_DIM * H_DIM, 256, 0, stream>>>(
        qhb, qlb, khb, klb, vhb, bias1, bias2, g_buf, ohb);

    // o -> out (2-term: o single plane, W split)
    gemm_out<<<dim3(2, 256), 256, 0, stream>>>(
        ohb, w_hi + 4 * 65536, w_lo + 4 * 65536, out);
}